// Round 1
// baseline (868.922 us; speedup 1.0000x reference)
//
#include <hip/hip_runtime.h>
#include <math.h>

#define TT 512
#define NB 32
#define NRSTEP 200
#define BIGV 1.0e8f

__device__ __forceinline__ float wshfl(float v, int srcLane) {
    return __shfl(v, srcLane, 64);
}

// ---------------- Kernel A: gather + HUX + v_out + per-b stats ----------------
// one wave per b; lane owns t = lane*8 .. lane*8+7 (contiguous chunk)
__global__ __launch_bounds__(64) void hux_stats_kernel(
    const float* __restrict__ pred_map,  // [B,1,T,128]
    const int*   __restrict__ lat_idx,   // [B,T]
    const float* __restrict__ omega,     // [B]
    const float* __restrict__ omni,      // [B,T]
    float*       __restrict__ out,       // v_out at [0, B*T)
    float*       __restrict__ ws)        // [B][4]: mae_b, sq_b, pcc_b, dtw_b
{
    const int b    = blockIdx.x;
    const int lane = threadIdx.x;
    const int t0   = lane * 8;

    // gather v_in
    float v[8];
    const int*   li = lat_idx + b * TT + t0;
    const float* pm = pred_map + (size_t)b * TT * 128 + (size_t)t0 * 128;
    #pragma unroll
    for (int k = 0; k < 8; ++k) {
        int idx = li[k];
        v[k] = pm[k * 128 + idx];
    }

    // HUX-f: v[t] += c/max(v[t],1) * (v[t+1]-v[t]),  c = dr*omega/dphi
    const float Kc = (float)(673089.75 / (2.0 * M_PI / 512.0));  // dr/dphi
    const float c  = Kc * omega[b];
    #pragma unroll 1
    for (int it = 0; it < NRSTEP; ++it) {
        float vn = wshfl(v[0], (lane + 1) & 63);  // old v[t0+8] (wraps 512->0)
        #pragma unroll
        for (int k = 0; k < 7; ++k) {
            float r = __builtin_amdgcn_rcpf(fmaxf(v[k], 1.0f));
            v[k] = v[k] + c * r * (v[k + 1] - v[k]);  // v[k+1] still old
        }
        float r7 = __builtin_amdgcn_rcpf(fmaxf(v[7], 1.0f));
        v[7] = v[7] + c * r7 * (vn - v[7]);
    }

    // write v_out (float32), coalesced float4
    float4* o4 = (float4*)(out + b * TT + t0);
    o4[0] = make_float4(v[0], v[1], v[2], v[3]);
    o4[1] = make_float4(v[4], v[5], v[6], v[7]);

    // per-b stats
    float x[8], y[8];
    const float* om = omni + b * TT + t0;
    float sx = 0.f, sy = 0.f;
    #pragma unroll
    for (int k = 0; k < 8; ++k) {
        x[k] = (om[k] - 200.0f) * 1e-3f;   // omni_scaled
        y[k] = (v[k] - 200.0f) * 1e-3f;    // v_out_scaled
        sx += x[k];
        sy += y[k];
    }
    #pragma unroll
    for (int m = 1; m < 64; m <<= 1) {
        sx += __shfl_xor(sx, m, 64);
        sy += __shfl_xor(sy, m, 64);
    }
    const float mx = sx * (1.0f / 512.0f);
    const float my = sy * (1.0f / 512.0f);

    float sab = 0.f, ssq = 0.f, snum = 0.f, sxx = 0.f, syy = 0.f;
    #pragma unroll
    for (int k = 0; k < 8; ++k) {
        float d = y[k] - x[k];
        sab += fabsf(d);
        ssq += d * d;
        float pc = y[k] - my;   // pred centered
        float tc = x[k] - mx;   // target centered
        snum += pc * tc;
        sxx  += tc * tc;
        syy  += pc * pc;
    }
    #pragma unroll
    for (int m = 1; m < 64; m <<= 1) {
        sab  += __shfl_xor(sab,  m, 64);
        ssq  += __shfl_xor(ssq,  m, 64);
        snum += __shfl_xor(snum, m, 64);
        sxx  += __shfl_xor(sxx,  m, 64);
        syy  += __shfl_xor(syy,  m, 64);
    }
    if (lane == 0) {
        ws[b * 4 + 0] = sab;
        ws[b * 4 + 1] = ssq;
        ws[b * 4 + 2] = snum / (sqrtf(syy) * sqrtf(sxx));
    }
}

// ---------------- Kernel B: soft-DTW, one wave per b ----------------
// rows i (= omni index) chunked 8/lane in registers; cols j (= v_out index) in LDS.
__global__ __launch_bounds__(64) void sdtw_kernel(
    const float* __restrict__ omni,
    const float* __restrict__ vout,   // v_out from kernel A (first B*T of d_out)
    float*       __restrict__ ws)
{
    const int b    = blockIdx.x;
    const int lane = threadIdx.x;
    const int base = lane * 8;

    __shared__ float sy[640];  // padded: index j + (j>>2), max 511+127=638

    float xk[8];
    #pragma unroll
    for (int k = 0; k < 8; ++k) {
        int j = base + k;
        float yv = (vout[b * TT + j] - 200.0f) * 1e-3f;
        sy[j + (j >> 2)] = yv;
        xk[k] = (omni[b * TT + j] - 200.0f) * 1e-3f;
    }
    __syncthreads();

    float A[8], B[8], C[8];
    #pragma unroll
    for (int k = 0; k < 8; ++k) { A[k] = BIGV; B[k] = BIGV; }
    if (lane == 0) {
        float d0 = xk[0] - sy[0];
        B[0] = d0 * d0;       // r(0,0) = D(0,0)
    }

    auto step = [&](float (&rm2)[8], float (&rm1)[8], float (&rn)[8], int p) {
        float bu = __shfl_up(rm1[7], 1, 64);  // lane l-1's row (base-1), diag p-1
        float bd = __shfl_up(rm2[7], 1, 64);  // lane l-1's row (base-1), diag p-2
        const int jbase = p - base;
        #pragma unroll
        for (int k = 0; k < 8; ++k) {
            int j  = jbase - k;
            int jc = j & 511;                    // in-bounds index; masked if invalid
            float yj = sy[jc + (jc >> 2)];
            float t  = xk[k] - yj;
            float d  = t * t;
            float up, dg;
            if (k == 0) {
                up = (lane == 0) ? BIGV : bu;
                dg = (lane == 0) ? BIGV : bd;
            } else {
                up = rm1[k - 1];
                dg = rm2[k - 1];
            }
            float lf = rm1[k];
            float m  = fminf(up, fminf(lf, dg));
            float s  = __expf((m - up) * 10.0f)
                     + __expf((m - lf) * 10.0f)
                     + __expf((m - dg) * 10.0f);
            float val = d + m - 0.1f * __logf(s);
            rn[k] = ((unsigned)j < 512u) ? val : BIGV;
        }
    };

    // p = 1 .. 1022; 3-buffer rotation, 340 groups of 3 (p=1..1020) + 2 tail
    int p = 1;
    #pragma unroll 1
    for (int g = 0; g < 340; ++g) {
        step(A, B, C, p);
        step(B, C, A, p + 1);
        step(C, A, B, p + 2);
        p += 3;
    }
    step(A, B, C, 1021);
    step(B, C, A, 1022);   // diag 1022 now in A

    if (lane == 63) ws[b * 4 + 3] = A[7];  // r_last[T-1] at i=511
}

// ---------------- Kernel C: final scalar reduction ----------------
__global__ __launch_bounds__(64) void finalize_kernel(
    const float* __restrict__ ws, float* __restrict__ out)
{
    const int lane = threadIdx.x;
    float mae = 0.f, sq = 0.f, pcc = 0.f, dtwa = 0.f;
    if (lane < NB) {
        mae  = ws[lane * 4 + 0];
        sq   = ws[lane * 4 + 1];
        pcc  = ws[lane * 4 + 2];
        dtwa = fabsf(ws[lane * 4 + 3]);
    }
    #pragma unroll
    for (int m = 1; m < 64; m <<= 1) {
        mae  += __shfl_xor(mae,  m, 64);
        sq   += __shfl_xor(sq,   m, 64);
        pcc  += __shfl_xor(pcc,  m, 64);
        dtwa += __shfl_xor(dtwa, m, 64);
    }
    if (lane == 0) {
        out[NB * TT + 0] = mae;                        // mae_loss
        out[NB * TT + 1] = 1.0f - pcc * (1.0f / 32.0f); // pcc_loss
        out[NB * TT + 2] = dtwa * (1.0f / 32.0f);       // dtw_loss
        out[NB * TT + 3] = sqrtf(sq);                   // rmse_loss
    }
}

extern "C" void kernel_launch(void* const* d_in, const int* in_sizes, int n_in,
                              void* d_out, int out_size, void* d_ws, size_t ws_size,
                              hipStream_t stream) {
    const float* pred_map = (const float*)d_in[0];
    const int*   lat_idx  = (const int*)d_in[1];
    const float* omega    = (const float*)d_in[2];
    const float* omni     = (const float*)d_in[3];
    float* out = (float*)d_out;
    float* ws  = (float*)d_ws;

    hux_stats_kernel<<<NB, 64, 0, stream>>>(pred_map, lat_idx, omega, omni, out, ws);
    sdtw_kernel<<<NB, 64, 0, stream>>>(omni, out, ws);
    finalize_kernel<<<1, 64, 0, stream>>>(ws, out);
}

// Round 2
// 284.179 us; speedup vs baseline: 3.0577x; 3.0577x over previous
//
#include <hip/hip_runtime.h>
#include <math.h>

#define TT 512
#define NB 32
#define NRSTEP 200
#define KSC 14.4269504f          // 10 * log2(e); u = KSC * R
#define BIGU 1.442695041e9f     // 1e8 * KSC

// ---------------- Fused kernel: gather + HUX + stats + soft-DTW ----------------
// one block (one wave) per batch b; lane owns rows/cols t = lane*8 .. lane*8+7
__global__ __launch_bounds__(64) void fused_kernel(
    const float* __restrict__ pred_map,  // [B,1,T,128]
    const int*   __restrict__ lat_idx,   // [B,T]
    const float* __restrict__ omega,     // [B]
    const float* __restrict__ omni,      // [B,T]
    float*       __restrict__ out,       // v_out at [0, B*T)
    float*       __restrict__ ws)        // [B][4]: mae_b, sq_b, pcc_b, dtw_b
{
    const int b    = blockIdx.x;
    const int lane = threadIdx.x;
    const int t0   = lane * 8;

    __shared__ float sy[TT];   // y = v_out_scaled (DTW columns)

    // ---- gather v_in ----
    float v[8];
    const int*   li = lat_idx + b * TT + t0;
    const float* pm = pred_map + (size_t)b * TT * 128 + (size_t)t0 * 128;
    #pragma unroll
    for (int k = 0; k < 8; ++k) v[k] = pm[k * 128 + li[k]];

    // ---- HUX-f: 200 upwind steps ----
    const float c = (float)(673089.75 / (2.0 * M_PI / 512.0)) * omega[b];
    #pragma unroll 1
    for (int it = 0; it < NRSTEP; ++it) {
        float vn = __shfl(v[0], (lane + 1) & 63, 64);  // old v[t0+8], wraps
        #pragma unroll
        for (int k = 0; k < 7; ++k) {
            float r = __builtin_amdgcn_rcpf(fmaxf(v[k], 1.0f));
            v[k] = v[k] + c * r * (v[k + 1] - v[k]);
        }
        float r7 = __builtin_amdgcn_rcpf(fmaxf(v[7], 1.0f));
        v[7] = v[7] + c * r7 * (vn - v[7]);
    }

    // ---- write v_out ----
    float4* o4 = (float4*)(out + b * TT + t0);
    o4[0] = make_float4(v[0], v[1], v[2], v[3]);
    o4[1] = make_float4(v[4], v[5], v[6], v[7]);

    // ---- scaled series + per-b stats ----
    float x[8], y8[8];
    const float* om = omni + b * TT + t0;
    float sx = 0.f, syy0 = 0.f;
    #pragma unroll
    for (int k = 0; k < 8; ++k) {
        x[k]  = (om[k] - 200.0f) * 1e-3f;   // omni_scaled (rows)
        y8[k] = (v[k] - 200.0f) * 1e-3f;    // v_out_scaled (cols)
        sy[t0 + k] = y8[k];
        sx += x[k];
        syy0 += y8[k];
    }
    #pragma unroll
    for (int m = 1; m < 64; m <<= 1) {
        sx   += __shfl_xor(sx, m, 64);
        syy0 += __shfl_xor(syy0, m, 64);
    }
    const float mx = sx * (1.0f / 512.0f);
    const float my = syy0 * (1.0f / 512.0f);

    float sab = 0.f, ssq = 0.f, snum = 0.f, sxx = 0.f, spp = 0.f;
    #pragma unroll
    for (int k = 0; k < 8; ++k) {
        float d = y8[k] - x[k];
        sab += fabsf(d);
        ssq += d * d;
        float pc = y8[k] - my;
        float tc = x[k] - mx;
        snum += pc * tc;
        sxx  += tc * tc;
        spp  += pc * pc;
    }
    #pragma unroll
    for (int m = 1; m < 64; m <<= 1) {
        sab  += __shfl_xor(sab,  m, 64);
        ssq  += __shfl_xor(ssq,  m, 64);
        snum += __shfl_xor(snum, m, 64);
        sxx  += __shfl_xor(sxx,  m, 64);
        spp  += __shfl_xor(spp,  m, 64);
    }
    if (lane == 0) {
        ws[b * 4 + 0] = sab;
        ws[b * 4 + 1] = ssq;
        ws[b * 4 + 2] = snum / (sqrtf(spp) * sqrtf(sxx));
    }
    __syncthreads();

    // ---- soft-DTW, skewed column sweep in u-domain (u = KSC * R) ----
    // lane l processes column j = s - l at step s; 8 rows/lane in registers.
    float P[8];                        // u(row, j-1) for lane's 8 rows
    #pragma unroll
    for (int k = 0; k < 8; ++k) P[k] = BIGU;
    float c7 = BIGU;                   // u(last own row, last processed col)
    float pU = BIGU;                   // shfl history: lane l-1's c7, two steps back
    float ycur = sy[0];                // y for this step (prefetched)

    #pragma unroll 1
    for (int s = 0; s < TT + 63; ++s) {
        float nU  = __shfl_up(c7, 1, 64);          // u(8l-1, j)   [from step s-1]
        float up0 = (lane == 0) ? BIGU : nU;
        float dg0 = (lane == 0) ? BIGU : pU;       // u(8l-1, j-1) [from step s-2]
        pU = nU;
        const int j = s - lane;
        int jn = j + 1; jn = jn < 0 ? 0 : (jn > 511 ? 511 : jn);
        float ynxt = sy[jn];                       // prefetch next step's y
        if ((unsigned)j < 512u) {
            const float yv = ycur;
            float uc  = up0;                       // "up" for cell 0
            float dgn = dg0;                       // "diag" for cell 0
            #pragma unroll
            for (int k = 0; k < 8; ++k) {
                float lf = P[k];                   // u(i, j-1)
                float dg = dgn;                    // u(i-1, j-1)
                dgn = lf;                          // becomes diag of next cell
                float lo = fminf(lf, dg);
                float hi = fmaxf(lf, dg);
                float t  = x[k] - yv;
                float t2k = t * t * KSC;           // KSC * D(i,j)
                float m   = fminf(uc, lo);         // min of three
                float mid = fmaxf(uc, lo);         // {mid,hi} = two non-min
                float e1  = __builtin_amdgcn_exp2f(m - mid);
                float e2  = __builtin_amdgcn_exp2f(m - hi);
                float s3  = 1.0f + e1 + e2;        // exp(0) term folded
                float sm  = m - __builtin_amdgcn_logf(s3);  // v_log = log2
                float u   = t2k + sm;
                if (k == 0) u = (lane == 0 && j == 0) ? t2k : u;  // R(0,0)=D(0,0)
                P[k] = u;
                uc   = u;
            }
            c7 = P[7];
        }
        ycur = ynxt;
    }

    if (lane == 63) ws[b * 4 + 3] = c7 * (1.0f / KSC);  // R(511,511)
}

// ---------------- final scalar reduction ----------------
__global__ __launch_bounds__(64) void finalize_kernel(
    const float* __restrict__ ws, float* __restrict__ out)
{
    const int lane = threadIdx.x;
    float mae = 0.f, sq = 0.f, pcc = 0.f, dtwa = 0.f;
    if (lane < NB) {
        mae  = ws[lane * 4 + 0];
        sq   = ws[lane * 4 + 1];
        pcc  = ws[lane * 4 + 2];
        dtwa = fabsf(ws[lane * 4 + 3]);
    }
    #pragma unroll
    for (int m = 1; m < 64; m <<= 1) {
        mae  += __shfl_xor(mae,  m, 64);
        sq   += __shfl_xor(sq,   m, 64);
        pcc  += __shfl_xor(pcc,  m, 64);
        dtwa += __shfl_xor(dtwa, m, 64);
    }
    if (lane == 0) {
        out[NB * TT + 0] = mae;                         // mae_loss
        out[NB * TT + 1] = 1.0f - pcc * (1.0f / 32.0f); // pcc_loss
        out[NB * TT + 2] = dtwa * (1.0f / 32.0f);       // dtw_loss
        out[NB * TT + 3] = sqrtf(sq);                   // rmse_loss
    }
}

extern "C" void kernel_launch(void* const* d_in, const int* in_sizes, int n_in,
                              void* d_out, int out_size, void* d_ws, size_t ws_size,
                              hipStream_t stream) {
    const float* pred_map = (const float*)d_in[0];
    const int*   lat_idx  = (const int*)d_in[1];
    const float* omega    = (const float*)d_in[2];
    const float* omni     = (const float*)d_in[3];
    float* out = (float*)d_out;
    float* ws  = (float*)d_ws;

    fused_kernel<<<NB, 64, 0, stream>>>(pred_map, lat_idx, omega, omni, out, ws);
    finalize_kernel<<<1, 64, 0, stream>>>(ws, out);
}

// Round 5
// 221.491 us; speedup vs baseline: 3.9231x; 1.2830x over previous
//
#include <hip/hip_runtime.h>
#include <math.h>

#define TT 512
#define NB 32
#define NRSTEP 200
#define KSC 14.4269504f          // 10 * log2(e); u = KSC * R

// DPP wave_shr:1  — lane i <- lane i-1, lane 0 gets 0 (rocPRIM scan idiom)
__device__ __forceinline__ float dpp_up1_f(float x) {
    return __int_as_float(__builtin_amdgcn_update_dpp(
        0, __float_as_int(x), 0x138, 0xf, 0xf, false));
}
__device__ __forceinline__ int dpp_up1_i(int x) {
    return __builtin_amdgcn_update_dpp(0, x, 0x138, 0xf, 0xf, false);
}

// ---------------- Fused kernel: gather + HUX + stats + soft-DTW + finalize ----
// one block (one wave) per batch b; lane owns rows/cols t = lane*8 .. lane*8+7
// ws layout: float acc[8] (mae, ssq, pcc_sum, dtw_sum, ...), int counter @ 32B
__global__ __launch_bounds__(64) void fused_kernel(
    const float* __restrict__ pred_map,  // [B,1,T,128]
    const int*   __restrict__ lat_idx,   // [B,T]
    const float* __restrict__ omega,     // [B]
    const float* __restrict__ omni,      // [B,T]
    float*       __restrict__ out,       // v_out at [0, B*T), scalars after
    float*       __restrict__ ws)
{
    const int b    = blockIdx.x;
    const int lane = threadIdx.x;
    const int t0   = lane * 8;

    __shared__ float sy[TT];   // y = v_out_scaled (DTW columns)

    // ---- gather v_in ----
    float v[8];
    const int*   li = lat_idx + b * TT + t0;
    const float* pm = pred_map + (size_t)b * TT * 128 + (size_t)t0 * 128;
    #pragma unroll
    for (int k = 0; k < 8; ++k) v[k] = pm[k * 128 + li[k]];

    // ---- HUX-f: 200 upwind steps ----
    const float c = (float)(673089.75 / (2.0 * M_PI / 512.0)) * omega[b];
    #pragma unroll 1
    for (int it = 0; it < NRSTEP; ++it) {
        float vn = __shfl(v[0], (lane + 1) & 63, 64);  // old v[t0+8], wraps
        #pragma unroll
        for (int k = 0; k < 7; ++k) {
            float r = __builtin_amdgcn_rcpf(fmaxf(v[k], 1.0f));
            v[k] = v[k] + c * r * (v[k + 1] - v[k]);
        }
        float r7 = __builtin_amdgcn_rcpf(fmaxf(v[7], 1.0f));
        v[7] = v[7] + c * r7 * (vn - v[7]);
    }

    // ---- write v_out ----
    float4* o4 = (float4*)(out + b * TT + t0);
    o4[0] = make_float4(v[0], v[1], v[2], v[3]);
    o4[1] = make_float4(v[4], v[5], v[6], v[7]);

    // ---- scaled series + per-b stats ----
    float x[8], y8[8];
    const float* om = omni + b * TT + t0;
    float sx = 0.f, syy0 = 0.f;
    #pragma unroll
    for (int k = 0; k < 8; ++k) {
        x[k]  = (om[k] - 200.0f) * 1e-3f;   // omni_scaled (rows)
        y8[k] = (v[k] - 200.0f) * 1e-3f;    // v_out_scaled (cols)
        sy[t0 + k] = y8[k];
        sx += x[k];
        syy0 += y8[k];
    }
    #pragma unroll
    for (int m = 1; m < 64; m <<= 1) {
        sx   += __shfl_xor(sx, m, 64);
        syy0 += __shfl_xor(syy0, m, 64);
    }
    const float mx = sx * (1.0f / 512.0f);
    const float my = syy0 * (1.0f / 512.0f);

    float sab = 0.f, ssq = 0.f, snum = 0.f, sxx = 0.f, spp = 0.f;
    #pragma unroll
    for (int k = 0; k < 8; ++k) {
        float d = y8[k] - x[k];
        sab += fabsf(d);
        ssq += d * d;
        float pc = y8[k] - my;
        float tc = x[k] - mx;
        snum += pc * tc;
        sxx  += tc * tc;
        spp  += pc * pc;
    }
    #pragma unroll
    for (int m = 1; m < 64; m <<= 1) {
        sab  += __shfl_xor(sab,  m, 64);
        ssq  += __shfl_xor(ssq,  m, 64);
        snum += __shfl_xor(snum, m, 64);
        sxx  += __shfl_xor(sxx,  m, 64);
        spp  += __shfl_xor(spp,  m, 64);
    }
    const float corr = snum / (sqrtf(spp) * sqrtf(sxx));
    __syncthreads();

    // ---- soft-DTW in w-domain: P[k] = 2^(E - u(row k, col j)),  u = KSC * R ----
    // (w_abs = P * 2^-E.)  lane l sweeps columns j = s - l; 8 rows/lane.
    // w=0 means u=inf (BIG). Post-compute renorm => snapshots normalized, P[7] in [1,2).
    float P[8];
    #pragma unroll
    for (int k = 0; k < 8; ++k) P[k] = 0.0f;
    int   E   = 0;
    float c7w = 0.0f;   int c7E = 0;    // own normalized boundary snapshot
    float pW  = 0.0f;   int pE  = 0;    // lane l-1 boundary, two steps back
    float ycur = sy[0];

    // exp2 factors for the current step, precomputed (off critical path)
    float fs[8];
    #pragma unroll
    for (int k = 0; k < 8; ++k) {
        float t = x[k] - ycur;
        fs[k] = __builtin_amdgcn_exp2f(t * t * (-KSC));
    }

    #pragma unroll 1
    for (int s = 0; s < TT + 63; ++s) {
        float nW = dpp_up1_f(c7w);       // lane l-1 post step s-1  (up for cell0)
        int   nE = dpp_up1_i(c7E);
        const int j = s - lane;
        int jn = j + 1; jn = jn < 0 ? 0 : (jn > 511 ? 511 : jn);
        float ynxt = sy[jn];             // prefetch next step's y

        if ((unsigned)j < 512u) {
            float wu, wd;
            if (lane == 0) {
                wu = 0.0f;
                wd = (j == 0) ? 1.0f : 0.0f;   // virtual origin: R(0,0)=D(0,0)
            } else if (j == 0) {
                E  = nE;                       // adopt neighbor scale
                wu = nW;                       // normalized snapshot, in [1,2)
                wd = 0.0f;                     // diag (8l-1,-1) = BIG
            } else {
                // neighbor value in OUR scale: w_n * 2^E = nW * 2^(E - nE)
                int du = E - nE; du = du > 125 ? 125 : du;
                int dd = E - pE; dd = dd > 125 ? 125 : dd;
                wu = ldexpf(nW, du);
                wd = ldexpf(pW, dd);
            }
            float uc = wu, dgn = wd;
            #pragma unroll
            for (int k = 0; k < 8; ++k) {
                float wl = P[k];
                float s3 = uc + (wl + dgn);    // (wl+dgn) off the serial chain
                float w  = fs[k] * s3;         // * 2^(-K*D)
                dgn = wl; P[k] = w; uc = w;
            }
            // post-compute renorm: P[7] -> [1,2); P[7] >= prod(fs)*wu > 0
            int ebits = (int)((__float_as_uint(P[7]) >> 23) & 255u);
            int dsh = 127 - ebits;
            E += dsh;
            #pragma unroll
            for (int k = 0; k < 8; ++k) P[k] = ldexpf(P[k], dsh);
            c7w = P[7]; c7E = E;
        }
        pW = nW; pE = nE;
        // precompute next step's exp2 factors (fills stall slots)
        #pragma unroll
        for (int k = 0; k < 8; ++k) {
            float t = x[k] - ynxt;
            fs[k] = __builtin_amdgcn_exp2f(t * t * (-KSC));
        }
        ycur = ynxt;
    }

    float dtwv = 0.0f;
    if (lane == 63) {
        float u = (float)E - __builtin_amdgcn_logf(P[7]);  // v_log = log2
        dtwv = fabsf(u) * (1.0f / KSC);                    // |R(511,511)|
    }

    // ---- cross-block accumulate + last-block finalize ----
    int* cnt = (int*)(ws + 8);
    if (lane == 0) {
        atomicAdd(&ws[0], sab);
        atomicAdd(&ws[1], ssq);
        atomicAdd(&ws[2], corr);
    }
    if (lane == 63) atomicAdd(&ws[3], dtwv);
    __threadfence();
    if (lane == 0) {
        int prev = atomicAdd(cnt, 1);
        if (prev == NB - 1) {
            __threadfence();
            float mae  = atomicAdd(&ws[0], 0.0f);
            float sq   = atomicAdd(&ws[1], 0.0f);
            float pccs = atomicAdd(&ws[2], 0.0f);
            float dtws = atomicAdd(&ws[3], 0.0f);
            out[NB * TT + 0] = mae;                          // mae_loss
            out[NB * TT + 1] = 1.0f - pccs * (1.0f / 32.0f); // pcc_loss
            out[NB * TT + 2] = dtws * (1.0f / 32.0f);        // dtw_loss
            out[NB * TT + 3] = sqrtf(sq);                    // rmse_loss
        }
    }
}

extern "C" void kernel_launch(void* const* d_in, const int* in_sizes, int n_in,
                              void* d_out, int out_size, void* d_ws, size_t ws_size,
                              hipStream_t stream) {
    const float* pred_map = (const float*)d_in[0];
    const int*   lat_idx  = (const int*)d_in[1];
    const float* omega    = (const float*)d_in[2];
    const float* omni     = (const float*)d_in[3];
    float* out = (float*)d_out;
    float* ws  = (float*)d_ws;

    hipMemsetAsync(ws, 0, 64, stream);
    fused_kernel<<<NB, 64, 0, stream>>>(pred_map, lat_idx, omega, omni, out, ws);
}

// Round 6
// 187.259 us; speedup vs baseline: 4.6402x; 1.1828x over previous
//
#include <hip/hip_runtime.h>
#include <math.h>

#define TT 512
#define NB 32
#define NRSTEP 200
#define KSC 14.4269504f          // 10 * log2(e); u = KSC * R

// DPP wave_shr:1  — lane i <- lane i-1, lane 0 gets 0 (verified R5: passed)
__device__ __forceinline__ float dpp_up1_f(float x) {
    return __int_as_float(__builtin_amdgcn_update_dpp(
        0, __float_as_int(x), 0x138, 0xf, 0xf, false));
}
__device__ __forceinline__ int dpp_up1_i(int x) {
    return __builtin_amdgcn_update_dpp(0, x, 0x138, 0xf, 0xf, false);
}
__device__ __forceinline__ float rdlane_f(float v, int lane) {
    return __int_as_float(__builtin_amdgcn_readlane(__float_as_int(v), lane));
}

// ---------------- Fused kernel: gather + HUX + stats + soft-DTW + finalize ----
// one block (one wave) per batch b; lane owns rows/cols t = lane*8 .. lane*8+7
// ws layout: float acc[8] (mae, ssq, pcc_sum, dtw_sum, ...), int counter @ 32B
__global__ __launch_bounds__(64) void fused_kernel(
    const float* __restrict__ pred_map,  // [B,1,T,128]
    const int*   __restrict__ lat_idx,   // [B,T]
    const float* __restrict__ omega,     // [B]
    const float* __restrict__ omni,      // [B,T]
    float*       __restrict__ out,       // v_out at [0, B*T), scalars after
    float*       __restrict__ ws)
{
    const int b    = blockIdx.x;
    const int lane = threadIdx.x;
    const int t0   = lane * 8;
    const bool lane0 = (lane == 0);

    // ---- gather v_in ----
    float v[8];
    const int*   li = lat_idx + b * TT + t0;
    const float* pm = pred_map + (size_t)b * TT * 128 + (size_t)t0 * 128;
    #pragma unroll
    for (int k = 0; k < 8; ++k) v[k] = pm[k * 128 + li[k]];

    // ---- HUX-f: 200 upwind steps ----
    const float c = (float)(673089.75 / (2.0 * M_PI / 512.0)) * omega[b];
    #pragma unroll 1
    for (int it = 0; it < NRSTEP; ++it) {
        float vn = __shfl(v[0], (lane + 1) & 63, 64);  // old v[t0+8], wraps
        #pragma unroll
        for (int k = 0; k < 7; ++k) {
            float r = __builtin_amdgcn_rcpf(fmaxf(v[k], 1.0f));
            v[k] = v[k] + c * r * (v[k + 1] - v[k]);
        }
        float r7 = __builtin_amdgcn_rcpf(fmaxf(v[7], 1.0f));
        v[7] = v[7] + c * r7 * (vn - v[7]);
    }

    // ---- write v_out ----
    float4* o4 = (float4*)(out + b * TT + t0);
    o4[0] = make_float4(v[0], v[1], v[2], v[3]);
    o4[1] = make_float4(v[4], v[5], v[6], v[7]);

    // ---- scaled series + per-b stats ----
    float x[8], y8[8];
    const float* om = omni + b * TT + t0;
    float sx = 0.f, syy0 = 0.f;
    #pragma unroll
    for (int k = 0; k < 8; ++k) {
        x[k]  = (om[k] - 200.0f) * 1e-3f;   // omni_scaled (rows)
        y8[k] = (v[k] - 200.0f) * 1e-3f;    // v_out_scaled (cols)
        sx += x[k];
        syy0 += y8[k];
    }
    #pragma unroll
    for (int m = 1; m < 64; m <<= 1) {
        sx   += __shfl_xor(sx, m, 64);
        syy0 += __shfl_xor(syy0, m, 64);
    }
    const float mx = sx * (1.0f / 512.0f);
    const float my = syy0 * (1.0f / 512.0f);

    float sab = 0.f, ssq = 0.f, snum = 0.f, sxx = 0.f, spp = 0.f;
    #pragma unroll
    for (int k = 0; k < 8; ++k) {
        float d = y8[k] - x[k];
        sab += fabsf(d);
        ssq += d * d;
        float pc = y8[k] - my;
        float tc = x[k] - mx;
        snum += pc * tc;
        sxx  += tc * tc;
        spp  += pc * pc;
    }
    #pragma unroll
    for (int m = 1; m < 64; m <<= 1) {
        sab  += __shfl_xor(sab,  m, 64);
        ssq  += __shfl_xor(ssq,  m, 64);
        snum += __shfl_xor(snum, m, 64);
        sxx  += __shfl_xor(sxx,  m, 64);
        spp  += __shfl_xor(spp,  m, 64);
    }
    const float corr = snum / (sqrtf(spp) * sqrtf(sxx));

    // ---- soft-DTW in w-domain, branchless + LDS-free ----
    // P[k] = 2^(E - u(row k, col j)), u = KSC*R; w_abs = P * 2^-E; w=0 <=> BIG.
    // lane l sweeps columns j = s - l; y flows down the wave via a DPP pipeline.
    float P[8];
    #pragma unroll
    for (int k = 0; k < 8; ++k) P[k] = 0.0f;
    int   E = 0;
    float c7w = 0.0f; int c7E = 0;      // own boundary snapshot (P[7], E)
    float pW  = 0.0f; int pE  = 0;      // lane l-1 snapshot, two steps back
    int vj = -lane;                     // j for the upcoming substep

    // y pipeline register: before step s, z(l) = y[s-l]
    float z = lane0 ? y8[0] : 0.0f;
    float fs[8];
    #pragma unroll
    for (int k = 0; k < 8; ++k) {
        float t = x[k] - z;
        fs[k] = __builtin_amdgcn_exp2f(t * t * (-KSC));
    }

    #pragma unroll 1
    for (int blk = 0; blk < 72; ++blk) {
        // feed values y[8*blk+1 .. 8*blk+8] for lane 0 (uniform source lanes)
        const int us  = blk < 63 ? blk : 63;        // garbage beyond range is
        const int us1 = blk < 62 ? blk + 1 : 63;    // never consumed by valid cells
        float f[8];
        f[0] = rdlane_f(y8[1], us);
        f[1] = rdlane_f(y8[2], us);
        f[2] = rdlane_f(y8[3], us);
        f[3] = rdlane_f(y8[4], us);
        f[4] = rdlane_f(y8[5], us);
        f[5] = rdlane_f(y8[6], us);
        f[6] = rdlane_f(y8[7], us);
        f[7] = rdlane_f(y8[0], us1);

        #pragma unroll
        for (int q = 0; q < 8; ++q) {
            float nW = dpp_up1_f(c7w);   // lane l-1 post step s-1 (up for cell0)
            int   nE = dpp_up1_i(c7E);
            const bool active = ((unsigned)vj < 512u);
            const bool adopt  = (vj == 0);
            E = adopt ? nE : E;          // adopt neighbor scale at first column
            int du = E - nE; du = du > 60 ? 60 : du;
            int dd = E - pE; dd = dd > 60 ? 60 : dd;
            float wu = ldexpf(nW, du);   // neighbor up in our scale
            float wd = ldexpf(pW, dd);   // neighbor diag (pW=0 at adoption)
            wd = (adopt && lane0) ? 1.0f : wd;   // virtual origin: R(0,0)=D(0,0)

            float uc = wu, dgn = wd;
            #pragma unroll
            for (int k = 0; k < 8; ++k) {
                float wl = P[k];
                float a  = fs[k] * (wl + dgn);   // off the serial chain
                float w  = fmaf(fs[k], uc, a);   // chain: one FMA per cell
                dgn = wl;
                P[k] = active ? w : wl;          // commit-mask (freeze outside)
                uc = w;
            }
            c7w = P[7]; c7E = E;
            pW = nW; pE = nE;

            // advance y pipeline (next step's y) and recompute fs (off-chain)
            float zn = dpp_up1_f(z);
            z = lane0 ? f[q] : zn;
            #pragma unroll
            for (int k = 0; k < 8; ++k) {
                float t = x[k] - z;
                fs[k] = __builtin_amdgcn_exp2f(t * t * (-KSC));
            }
            ++vj;
        }
        // per-block renorm: P[7] -> [1,2); pair (P,E) stays consistent
        int ebits = (int)((__float_as_uint(P[7]) >> 23) & 255u);
        int dsh = 127 - ebits;
        E += dsh;
        #pragma unroll
        for (int k = 0; k < 8; ++k) P[k] = ldexpf(P[k], dsh);
    }

    float dtwv = 0.0f;
    if (lane == 63) {
        float u = (float)E - __builtin_amdgcn_logf(P[7]);  // v_log = log2
        dtwv = fabsf(u) * (1.0f / KSC);                    // |R(511,511)|
    }

    // ---- cross-block accumulate + last-block finalize ----
    int* cnt = (int*)(ws + 8);
    if (lane == 0) {
        atomicAdd(&ws[0], sab);
        atomicAdd(&ws[1], ssq);
        atomicAdd(&ws[2], corr);
    }
    if (lane == 63) atomicAdd(&ws[3], dtwv);
    __threadfence();
    if (lane == 0) {
        int prev = atomicAdd(cnt, 1);
        if (prev == NB - 1) {
            __threadfence();
            float mae  = atomicAdd(&ws[0], 0.0f);
            float sq   = atomicAdd(&ws[1], 0.0f);
            float pccs = atomicAdd(&ws[2], 0.0f);
            float dtws = atomicAdd(&ws[3], 0.0f);
            out[NB * TT + 0] = mae;                          // mae_loss
            out[NB * TT + 1] = 1.0f - pccs * (1.0f / 32.0f); // pcc_loss
            out[NB * TT + 2] = dtws * (1.0f / 32.0f);        // dtw_loss
            out[NB * TT + 3] = sqrtf(sq);                    // rmse_loss
        }
    }
}

extern "C" void kernel_launch(void* const* d_in, const int* in_sizes, int n_in,
                              void* d_out, int out_size, void* d_ws, size_t ws_size,
                              hipStream_t stream) {
    const float* pred_map = (const float*)d_in[0];
    const int*   lat_idx  = (const int*)d_in[1];
    const float* omega    = (const float*)d_in[2];
    const float* omni     = (const float*)d_in[3];
    float* out = (float*)d_out;
    float* ws  = (float*)d_ws;

    hipMemsetAsync(ws, 0, 64, stream);
    fused_kernel<<<NB, 64, 0, stream>>>(pred_map, lat_idx, omega, omni, out, ws);
}

// Round 7
// 170.872 us; speedup vs baseline: 5.0852x; 1.0959x over previous
//
#include <hip/hip_runtime.h>
#include <math.h>

#define TT 512
#define NB 32
#define NRSTEP 200
#define KSC 14.4269504f          // 10 * log2(e); u = KSC * R

typedef float float2v __attribute__((ext_vector_type(2)));

// DPP wave_shr:1  — lane i <- lane i-1, lane 0 gets 0 (verified R5/R6: exact)
__device__ __forceinline__ float dpp_up1_f(float x) {
    return __int_as_float(__builtin_amdgcn_update_dpp(
        0, __float_as_int(x), 0x138, 0xf, 0xf, false));
}
__device__ __forceinline__ int dpp_up1_i(int x) {
    return __builtin_amdgcn_update_dpp(0, x, 0x138, 0xf, 0xf, false);
}
__device__ __forceinline__ float rdlane_f(float v, int lane) {
    return __int_as_float(__builtin_amdgcn_readlane(__float_as_int(v), lane));
}

// ---------------- Fused kernel: gather + HUX + stats + soft-DTW + finalize ----
// one block (one wave) per batch b; lane owns rows/cols t = lane*8 .. lane*8+7
// launch_bounds(64,1): 1 wave/EU floor -> full VGPR budget for sw-pipelining
__global__ __launch_bounds__(64, 1) void fused_kernel(
    const float* __restrict__ pred_map,  // [B,1,T,128]
    const int*   __restrict__ lat_idx,   // [B,T]
    const float* __restrict__ omega,     // [B]
    const float* __restrict__ omni,      // [B,T]
    float*       __restrict__ out,       // v_out at [0, B*T), scalars after
    float*       __restrict__ ws)
{
    const int b    = blockIdx.x;
    const int lane = threadIdx.x;
    const int t0   = lane * 8;
    const bool lane0 = (lane == 0);

    // ---- gather v_in ----
    float v[8];
    const int*   li = lat_idx + b * TT + t0;
    const float* pm = pred_map + (size_t)b * TT * 128 + (size_t)t0 * 128;
    #pragma unroll
    for (int k = 0; k < 8; ++k) v[k] = pm[k * 128 + li[k]];

    // ---- HUX-f: 200 upwind steps ----
    const float c = (float)(673089.75 / (2.0 * M_PI / 512.0)) * omega[b];
    #pragma unroll 1
    for (int it = 0; it < NRSTEP; ++it) {
        float vn = __shfl(v[0], (lane + 1) & 63, 64);  // old v[t0+8], wraps
        #pragma unroll
        for (int k = 0; k < 7; ++k) {
            float r = __builtin_amdgcn_rcpf(fmaxf(v[k], 1.0f));
            v[k] = v[k] + c * r * (v[k + 1] - v[k]);
        }
        float r7 = __builtin_amdgcn_rcpf(fmaxf(v[7], 1.0f));
        v[7] = v[7] + c * r7 * (vn - v[7]);
    }

    // ---- write v_out ----
    float4* o4 = (float4*)(out + b * TT + t0);
    o4[0] = make_float4(v[0], v[1], v[2], v[3]);
    o4[1] = make_float4(v[4], v[5], v[6], v[7]);

    // ---- scaled series + per-b stats ----
    float x[8], y8[8];
    const float* om = omni + b * TT + t0;
    float sx = 0.f, syy0 = 0.f;
    #pragma unroll
    for (int k = 0; k < 8; ++k) {
        x[k]  = (om[k] - 200.0f) * 1e-3f;   // omni_scaled (rows)
        y8[k] = (v[k] - 200.0f) * 1e-3f;    // v_out_scaled (cols)
        sx += x[k];
        syy0 += y8[k];
    }
    #pragma unroll
    for (int m = 1; m < 64; m <<= 1) {
        sx   += __shfl_xor(sx, m, 64);
        syy0 += __shfl_xor(syy0, m, 64);
    }
    const float mx = sx * (1.0f / 512.0f);
    const float my = syy0 * (1.0f / 512.0f);

    float sab = 0.f, ssq = 0.f, snum = 0.f, sxx = 0.f, spp = 0.f;
    #pragma unroll
    for (int k = 0; k < 8; ++k) {
        float d = y8[k] - x[k];
        sab += fabsf(d);
        ssq += d * d;
        float pc = y8[k] - my;
        float tc = x[k] - mx;
        snum += pc * tc;
        sxx  += tc * tc;
        spp  += pc * pc;
    }
    #pragma unroll
    for (int m = 1; m < 64; m <<= 1) {
        sab  += __shfl_xor(sab,  m, 64);
        ssq  += __shfl_xor(ssq,  m, 64);
        snum += __shfl_xor(snum, m, 64);
        sxx  += __shfl_xor(sxx,  m, 64);
        spp  += __shfl_xor(spp,  m, 64);
    }
    const float corr = snum / (sqrtf(spp) * sqrtf(sxx));

    // ---- soft-DTW in w-domain, branchless + LDS-free ----
    // P[k] = 2^(E - u(row k, col j)), u = KSC*R; w_abs = P * 2^-E; w=0 <=> BIG.
    // lane l sweeps columns j = s - l; y flows down the wave via a DPP pipeline.
    // No commit masks: pre-active lanes stay 0 naturally; post-active garbage
    // is bounded and never consumed (snapshots c7w/c7E are pub-guarded).
    float2v x2[4];
    #pragma unroll
    for (int i = 0; i < 4; ++i) { x2[i].x = x[2 * i]; x2[i].y = x[2 * i + 1]; }

    float P[8];
    #pragma unroll
    for (int k = 0; k < 8; ++k) P[k] = 0.0f;
    int   E = 0;
    float c7w = 0.0f; int c7E = 0;      // own boundary snapshot (P[7], E)
    float pW  = 0.0f; int pE  = 0;      // lane l-1 snapshot, two steps back
    int vj = -lane;                     // j for the upcoming substep

    // y pipeline register: before step s, z(l) = y[s-l]
    float z = lane0 ? y8[0] : 0.0f;
    float fs[8];
    #pragma unroll
    for (int i = 0; i < 4; ++i) {
        float2v zz; zz.x = z; zz.y = z;
        float2v t = x2[i] - zz;
        float2v a = (t * t) * (float2v){-KSC, -KSC};
        fs[2 * i]     = __builtin_amdgcn_exp2f(a.x);
        fs[2 * i + 1] = __builtin_amdgcn_exp2f(a.y);
    }

    #pragma unroll 1
    for (int blk = 0; blk < 72; ++blk) {
        // feed values y[8*blk+1 .. 8*blk+8] for lane 0 (uniform source lanes)
        const int us  = blk < 63 ? blk : 63;        // garbage beyond range is
        const int us1 = blk < 62 ? blk + 1 : 63;    // never consumed by valid cells
        float f[8];
        f[0] = rdlane_f(y8[1], us);
        f[1] = rdlane_f(y8[2], us);
        f[2] = rdlane_f(y8[3], us);
        f[3] = rdlane_f(y8[4], us);
        f[4] = rdlane_f(y8[5], us);
        f[5] = rdlane_f(y8[6], us);
        f[6] = rdlane_f(y8[7], us);
        f[7] = rdlane_f(y8[0], us1);

        #pragma unroll
        for (int q = 0; q < 8; ++q) {
            float nW = dpp_up1_f(c7w);   // lane l-1 post step s-1 (up for cell0)
            int   nE = dpp_up1_i(c7E);
            const bool adopt = (vj == 0);
            const bool pub   = ((unsigned)vj < 512u);
            E = adopt ? nE : E;          // adopt neighbor scale at first column
            int du = E - nE; du = du > 60 ? 60 : du;
            int dd = E - pE; dd = dd > 60 ? 60 : dd;
            float wu = ldexpf(nW, du);   // neighbor up in our scale
            float wd = ldexpf(pW, dd);   // neighbor diag (pW=0 at adoption)
            wd = (adopt && lane0) ? 1.0f : wd;   // virtual origin: R(0,0)=D(0,0)

            float uc = wu, dgn = wd;
            #pragma unroll
            for (int k = 0; k < 8; ++k) {
                float wl = P[k];
                float a  = fs[k] * (wl + dgn);   // off the serial chain
                float w  = fmaf(fs[k], uc, a);   // chain: one FMA per cell
                dgn = wl;
                P[k] = w;                        // unconditional commit
                uc = w;
            }
            c7w = pub ? P[7] : c7w;              // snapshot only while valid
            c7E = pub ? E    : c7E;
            pW = nW; pE = nE;

            // advance y pipeline (next step's y) and recompute fs (off-chain)
            float zn = dpp_up1_f(z);
            z = lane0 ? f[q] : zn;
            #pragma unroll
            for (int i = 0; i < 4; ++i) {
                float2v zz; zz.x = z; zz.y = z;
                float2v t = x2[i] - zz;
                float2v a = (t * t) * (float2v){-KSC, -KSC};
                fs[2 * i]     = __builtin_amdgcn_exp2f(a.x);
                fs[2 * i + 1] = __builtin_amdgcn_exp2f(a.y);
            }
            ++vj;
        }
        // per-block renorm: P[7] -> [1,2); (P,E) pair stays consistent
        int ebits = (int)((__float_as_uint(P[7]) >> 23) & 255u);
        int dsh = 127 - ebits;
        E += dsh;
        #pragma unroll
        for (int k = 0; k < 8; ++k) P[k] = ldexpf(P[k], dsh);
    }

    float dtwv = 0.0f;
    if (lane == 63) {
        // read the frozen snapshot (P/E may hold one substep of garbage past
        // the last valid column)
        float u = (float)c7E - __builtin_amdgcn_logf(c7w);  // v_log = log2
        dtwv = fabsf(u) * (1.0f / KSC);                     // |R(511,511)|
    }

    // ---- cross-block accumulate + last-block finalize ----
    int* cnt = (int*)(ws + 8);
    if (lane == 0) {
        atomicAdd(&ws[0], sab);
        atomicAdd(&ws[1], ssq);
        atomicAdd(&ws[2], corr);
    }
    if (lane == 63) atomicAdd(&ws[3], dtwv);
    __threadfence();
    if (lane == 0) {
        int prev = atomicAdd(cnt, 1);
        if (prev == NB - 1) {
            __threadfence();
            float mae  = atomicAdd(&ws[0], 0.0f);
            float sq   = atomicAdd(&ws[1], 0.0f);
            float pccs = atomicAdd(&ws[2], 0.0f);
            float dtws = atomicAdd(&ws[3], 0.0f);
            out[NB * TT + 0] = mae;                          // mae_loss
            out[NB * TT + 1] = 1.0f - pccs * (1.0f / 32.0f); // pcc_loss
            out[NB * TT + 2] = dtws * (1.0f / 32.0f);        // dtw_loss
            out[NB * TT + 3] = sqrtf(sq);                    // rmse_loss
        }
    }
}

extern "C" void kernel_launch(void* const* d_in, const int* in_sizes, int n_in,
                              void* d_out, int out_size, void* d_ws, size_t ws_size,
                              hipStream_t stream) {
    const float* pred_map = (const float*)d_in[0];
    const int*   lat_idx  = (const int*)d_in[1];
    const float* omega    = (const float*)d_in[2];
    const float* omni     = (const float*)d_in[3];
    float* out = (float*)d_out;
    float* ws  = (float*)d_ws;

    hipMemsetAsync(ws, 0, 64, stream);
    fused_kernel<<<NB, 64, 0, stream>>>(pred_map, lat_idx, omega, omni, out, ws);
}

// Round 8
// 163.022 us; speedup vs baseline: 5.3301x; 1.0482x over previous
//
#include <hip/hip_runtime.h>
#include <math.h>

#define TT 512
#define NB 32
#define NRSTEP 200
#define KSC 14.4269504f          // 10 * log2(e); u = KSC * R

// Schraudolph fast 2^a for a in [-5, 0]: bitcast(int(a*2^23 + 127*2^23 - 366393))
// max rel err ~3%, value at a=0 is 0.970 (<1, keeps garbage contractive)
#define SCHR_SCALE (-KSC * 8388608.0f)   // folds -K into the 2^23 scale
#define SCHR_OFF   1064986823.0f         // 127*2^23 - 366393

typedef float float2v __attribute__((ext_vector_type(2)));

// DPP wave_shr:1  — lane i <- lane i-1, lane 0 gets 0 (verified R5/R6: exact)
__device__ __forceinline__ float dpp_up1_f(float x) {
    return __int_as_float(__builtin_amdgcn_update_dpp(
        0, __float_as_int(x), 0x138, 0xf, 0xf, false));
}
__device__ __forceinline__ int dpp_up1_i(int x) {
    return __builtin_amdgcn_update_dpp(0, x, 0x138, 0xf, 0xf, false);
}
__device__ __forceinline__ float rdlane_f(float v, int lane) {
    return __int_as_float(__builtin_amdgcn_readlane(__float_as_int(v), lane));
}

// ---------------- Fused kernel: gather + HUX + stats + soft-DTW + finalize ----
// one block (one wave) per batch b; lane owns rows/cols t = lane*8 .. lane*8+7
__global__ __launch_bounds__(64, 1) void fused_kernel(
    const float* __restrict__ pred_map,  // [B,1,T,128]
    const int*   __restrict__ lat_idx,   // [B,T]
    const float* __restrict__ omega,     // [B]
    const float* __restrict__ omni,      // [B,T]
    float*       __restrict__ out,       // v_out at [0, B*T), scalars after
    float*       __restrict__ ws)
{
    const int b    = blockIdx.x;
    const int lane = threadIdx.x;
    const int t0   = lane * 8;
    const bool lane0 = (lane == 0);

    // ---- gather v_in ----
    float v[8];
    const int*   li = lat_idx + b * TT + t0;
    const float* pm = pred_map + (size_t)b * TT * 128 + (size_t)t0 * 128;
    #pragma unroll
    for (int k = 0; k < 8; ++k) v[k] = pm[k * 128 + li[k]];

    // ---- HUX-f: 200 upwind steps ----
    const float c = (float)(673089.75 / (2.0 * M_PI / 512.0)) * omega[b];
    #pragma unroll 1
    for (int it = 0; it < NRSTEP; ++it) {
        float vn = __shfl(v[0], (lane + 1) & 63, 64);  // old v[t0+8], wraps
        #pragma unroll
        for (int k = 0; k < 7; ++k) {
            float r = __builtin_amdgcn_rcpf(fmaxf(v[k], 1.0f));
            v[k] = v[k] + c * r * (v[k + 1] - v[k]);
        }
        float r7 = __builtin_amdgcn_rcpf(fmaxf(v[7], 1.0f));
        v[7] = v[7] + c * r7 * (vn - v[7]);
    }

    // ---- write v_out ----
    float4* o4 = (float4*)(out + b * TT + t0);
    o4[0] = make_float4(v[0], v[1], v[2], v[3]);
    o4[1] = make_float4(v[4], v[5], v[6], v[7]);

    // ---- scaled series + per-b stats ----
    float x[8], y8[8];
    const float* om = omni + b * TT + t0;
    float sx = 0.f, syy0 = 0.f;
    #pragma unroll
    for (int k = 0; k < 8; ++k) {
        x[k]  = (om[k] - 200.0f) * 1e-3f;   // omni_scaled (rows)
        y8[k] = (v[k] - 200.0f) * 1e-3f;    // v_out_scaled (cols)
        sx += x[k];
        syy0 += y8[k];
    }
    #pragma unroll
    for (int m = 1; m < 64; m <<= 1) {
        sx   += __shfl_xor(sx, m, 64);
        syy0 += __shfl_xor(syy0, m, 64);
    }
    const float mx = sx * (1.0f / 512.0f);
    const float my = syy0 * (1.0f / 512.0f);

    float sab = 0.f, ssq = 0.f, snum = 0.f, sxx = 0.f, spp = 0.f;
    #pragma unroll
    for (int k = 0; k < 8; ++k) {
        float d = y8[k] - x[k];
        sab += fabsf(d);
        ssq += d * d;
        float pc = y8[k] - my;
        float tc = x[k] - mx;
        snum += pc * tc;
        sxx  += tc * tc;
        spp  += pc * pc;
    }
    #pragma unroll
    for (int m = 1; m < 64; m <<= 1) {
        sab  += __shfl_xor(sab,  m, 64);
        ssq  += __shfl_xor(ssq,  m, 64);
        snum += __shfl_xor(snum, m, 64);
        sxx  += __shfl_xor(sxx,  m, 64);
        spp  += __shfl_xor(spp,  m, 64);
    }
    const float corr = snum / (sqrtf(spp) * sqrtf(sxx));

    // ---- soft-DTW in w-domain, branchless + LDS-free + trans-free inner loop --
    // P[k] = 2^(E - u(row k, col j)), u = KSC*R; w_abs = P * 2^-E; w=0 <=> BIG.
    // lane l sweeps columns j = s - l; y flows down the wave via a DPP pipeline.
    // fs via Schraudolph bit-trick (no v_exp_f32 on the issue stream).
    float2v x2[4];
    #pragma unroll
    for (int i = 0; i < 4; ++i) { x2[i].x = x[2 * i]; x2[i].y = x[2 * i + 1]; }

    float P[8];
    #pragma unroll
    for (int k = 0; k < 8; ++k) P[k] = 0.0f;
    int   E = 0;
    float c7w = 0.0f; int c7E = 0;      // own boundary snapshot (P[7], E)
    float pW  = 0.0f; int pE  = 0;      // lane l-1 snapshot, two steps back
    int vj = -lane;                     // j for the upcoming substep

    // y pipeline register: before step s, z(l) = y[s-l]
    float z = lane0 ? y8[0] : 0.0f;
    float fs[8];
    #pragma unroll
    for (int i = 0; i < 4; ++i) {
        float2v zz; zz.x = z; zz.y = z;
        float2v t  = x2[i] - zz;
        float2v t2 = t * t;
        float2v h  = t2 * (float2v){SCHR_SCALE, SCHR_SCALE}
                   + (float2v){SCHR_OFF, SCHR_OFF};
        fs[2 * i]     = __int_as_float((int)h.x);
        fs[2 * i + 1] = __int_as_float((int)h.y);
    }

    #pragma unroll 1
    for (int blk = 0; blk < 72; ++blk) {
        // feed values y[8*blk+1 .. 8*blk+8] for lane 0 (uniform source lanes)
        const int us  = blk < 63 ? blk : 63;        // garbage beyond range is
        const int us1 = blk < 62 ? blk + 1 : 63;    // never consumed by valid cells
        float f[8];
        f[0] = rdlane_f(y8[1], us);
        f[1] = rdlane_f(y8[2], us);
        f[2] = rdlane_f(y8[3], us);
        f[3] = rdlane_f(y8[4], us);
        f[4] = rdlane_f(y8[5], us);
        f[5] = rdlane_f(y8[6], us);
        f[6] = rdlane_f(y8[7], us);
        f[7] = rdlane_f(y8[0], us1);

        #pragma unroll
        for (int q = 0; q < 8; ++q) {
            float nW = dpp_up1_f(c7w);   // lane l-1 post step s-1 (up for cell0)
            int   nE = dpp_up1_i(c7E);
            const bool adopt = (vj == 0);
            const bool pub   = ((unsigned)vj < 512u);
            E = adopt ? nE : E;          // adopt neighbor scale at first column
            int du = E - nE; du = du > 60 ? 60 : du;
            int dd = E - pE; dd = dd > 60 ? 60 : dd;
            float wu = ldexpf(nW, du);   // neighbor up in our scale
            float wd = ldexpf(pW, dd);   // neighbor diag (pW=0 at adoption)
            wd = (adopt && lane0) ? 1.0f : wd;   // virtual origin: R(0,0)=D(0,0)

            float uc = wu, dgn = wd;
            #pragma unroll
            for (int k = 0; k < 8; ++k) {
                float wl = P[k];
                float a  = fs[k] * (wl + dgn);   // off the serial chain
                float w  = fmaf(fs[k], uc, a);   // chain: one FMA per cell
                dgn = wl;
                P[k] = w;                        // unconditional commit
                uc = w;
            }
            c7w = pub ? P[7] : c7w;              // snapshot only while valid
            c7E = pub ? E    : c7E;
            pW = nW; pE = nE;

            // advance y pipeline and recompute fs (pure VALU, off the chain)
            float zn = dpp_up1_f(z);
            z = lane0 ? f[q] : zn;
            #pragma unroll
            for (int i = 0; i < 4; ++i) {
                float2v zz; zz.x = z; zz.y = z;
                float2v t  = x2[i] - zz;
                float2v t2 = t * t;
                float2v h  = t2 * (float2v){SCHR_SCALE, SCHR_SCALE}
                           + (float2v){SCHR_OFF, SCHR_OFF};
                fs[2 * i]     = __int_as_float((int)h.x);
                fs[2 * i + 1] = __int_as_float((int)h.y);
            }
            ++vj;
        }
        // per-block renorm: P[7] -> [1,2); (P,E) pair stays consistent
        int ebits = (int)((__float_as_uint(P[7]) >> 23) & 255u);
        int dsh = 127 - ebits;
        E += dsh;
        #pragma unroll
        for (int k = 0; k < 8; ++k) P[k] = ldexpf(P[k], dsh);
    }

    float dtwv = 0.0f;
    if (lane == 63) {
        // read the frozen snapshot (P/E may hold garbage past last valid column)
        float u = (float)c7E - __builtin_amdgcn_logf(c7w);  // v_log = log2
        dtwv = fabsf(u) * (1.0f / KSC);                     // |R(511,511)|
    }

    // ---- cross-block accumulate + last-block finalize ----
    int* cnt = (int*)(ws + 8);
    if (lane == 0) {
        atomicAdd(&ws[0], sab);
        atomicAdd(&ws[1], ssq);
        atomicAdd(&ws[2], corr);
    }
    if (lane == 63) atomicAdd(&ws[3], dtwv);
    __threadfence();
    if (lane == 0) {
        int prev = atomicAdd(cnt, 1);
        if (prev == NB - 1) {
            __threadfence();
            float mae  = atomicAdd(&ws[0], 0.0f);
            float sq   = atomicAdd(&ws[1], 0.0f);
            float pccs = atomicAdd(&ws[2], 0.0f);
            float dtws = atomicAdd(&ws[3], 0.0f);
            out[NB * TT + 0] = mae;                          // mae_loss
            out[NB * TT + 1] = 1.0f - pccs * (1.0f / 32.0f); // pcc_loss
            out[NB * TT + 2] = dtws * (1.0f / 32.0f);        // dtw_loss
            out[NB * TT + 3] = sqrtf(sq);                    // rmse_loss
        }
    }
}

extern "C" void kernel_launch(void* const* d_in, const int* in_sizes, int n_in,
                              void* d_out, int out_size, void* d_ws, size_t ws_size,
                              hipStream_t stream) {
    const float* pred_map = (const float*)d_in[0];
    const int*   lat_idx  = (const int*)d_in[1];
    const float* omega    = (const float*)d_in[2];
    const float* omni     = (const float*)d_in[3];
    float* out = (float*)d_out;
    float* ws  = (float*)d_ws;

    hipMemsetAsync(ws, 0, 64, stream);
    fused_kernel<<<NB, 64, 0, stream>>>(pred_map, lat_idx, omega, omni, out, ws);
}

// Round 10
// 153.621 us; speedup vs baseline: 5.6563x; 1.0612x over previous
//
#include <hip/hip_runtime.h>
#include <math.h>

#define TT 512
#define NB 32
#define NRSTEP 200
#define KSC 14.4269504f          // 10 * log2(e); u = KSC * R

// Schraudolph fast 2^a for a in [-5, 0] (verified R8): bitcast(int(a*2^23 + OFF))
#define SCHR_SCALE (-KSC * 8388608.0f)
#define SCHR_OFF   1064986823.0f         // 127*2^23 - 366393

typedef float float2v __attribute__((ext_vector_type(2)));

// DPP wave_shr:1  — lane i <- lane i-1, lane 0 gets 0 (verified R5..R8)
__device__ __forceinline__ float dpp_up1_f(float x) {
    return __int_as_float(__builtin_amdgcn_update_dpp(
        0, __float_as_int(x), 0x138, 0xf, 0xf, false));
}
__device__ __forceinline__ int dpp_up1_i(int x) {
    return __builtin_amdgcn_update_dpp(0, x, 0x138, 0xf, 0xf, false);
}
__device__ __forceinline__ float rdlane_f(float v, int lane) {
    return __int_as_float(__builtin_amdgcn_readlane(__float_as_int(v), lane));
}
// 2^e for e in [-126, 127] via exponent-field construction (no trans op)
__device__ __forceinline__ float exp2i(int e) {
    return __int_as_float((e + 127) << 23);
}

// ---------------- Fused kernel: gather + HUX + stats + soft-DTW + finalize ----
// one block (one wave) per batch b; lane owns rows t = lane*8 .. lane*8+7
// DP: two intra-lane groups, packed: P[k] = {w(row k, col j0), w(row k+4, col
// j0-1)} * 2^E, j0 = s - 2*lane. Exact per-substep exponent tracking (R8
// scheme): published pairs (c7w,c7E) and (pW,pE) are always self-consistent.
__global__ __launch_bounds__(64, 1) void fused_kernel(
    const float* __restrict__ pred_map,  // [B,1,T,128]
    const int*   __restrict__ lat_idx,   // [B,T]
    const float* __restrict__ omega,     // [B]
    const float* __restrict__ omni,      // [B,T]
    float*       __restrict__ out,       // v_out at [0, B*T), scalars after
    float*       __restrict__ ws)
{
    const int b    = blockIdx.x;
    const int lane = threadIdx.x;
    const int t0   = lane * 8;
    const bool lane0 = (lane == 0);

    // ---- gather v_in ----
    float v[8];
    const int*   li = lat_idx + b * TT + t0;
    const float* pm = pred_map + (size_t)b * TT * 128 + (size_t)t0 * 128;
    #pragma unroll
    for (int k = 0; k < 8; ++k) v[k] = pm[k * 128 + li[k]];

    // ---- HUX-f: 200 upwind steps (proven R5..R8, untouched) ----
    const float c = (float)(673089.75 / (2.0 * M_PI / 512.0)) * omega[b];
    #pragma unroll 1
    for (int it = 0; it < NRSTEP; ++it) {
        float vn = __shfl(v[0], (lane + 1) & 63, 64);  // old v[t0+8], wraps
        #pragma unroll
        for (int k = 0; k < 7; ++k) {
            float r = __builtin_amdgcn_rcpf(fmaxf(v[k], 1.0f));
            v[k] = v[k] + c * r * (v[k + 1] - v[k]);
        }
        float r7 = __builtin_amdgcn_rcpf(fmaxf(v[7], 1.0f));
        v[7] = v[7] + c * r7 * (vn - v[7]);
    }

    // ---- write v_out ----
    float4* o4 = (float4*)(out + b * TT + t0);
    o4[0] = make_float4(v[0], v[1], v[2], v[3]);
    o4[1] = make_float4(v[4], v[5], v[6], v[7]);

    // ---- scaled series + per-b stats ----
    float x[8], y8[8];
    const float* om = omni + b * TT + t0;
    float sx = 0.f, syy0 = 0.f;
    #pragma unroll
    for (int k = 0; k < 8; ++k) {
        x[k]  = (om[k] - 200.0f) * 1e-3f;   // omni_scaled (rows)
        y8[k] = (v[k] - 200.0f) * 1e-3f;    // v_out_scaled (cols)
        sx += x[k];
        syy0 += y8[k];
    }
    #pragma unroll
    for (int m = 1; m < 64; m <<= 1) {
        sx   += __shfl_xor(sx, m, 64);
        syy0 += __shfl_xor(syy0, m, 64);
    }
    const float mx = sx * (1.0f / 512.0f);
    const float my = syy0 * (1.0f / 512.0f);

    float sab = 0.f, ssq = 0.f, snum = 0.f, sxx = 0.f, spp = 0.f;
    #pragma unroll
    for (int k = 0; k < 8; ++k) {
        float d = y8[k] - x[k];
        sab += fabsf(d);
        ssq += d * d;
        float pc = y8[k] - my;
        float tc = x[k] - mx;
        snum += pc * tc;
        sxx  += tc * tc;
        spp  += pc * pc;
    }
    #pragma unroll
    for (int m = 1; m < 64; m <<= 1) {
        sab  += __shfl_xor(sab,  m, 64);
        ssq  += __shfl_xor(ssq,  m, 64);
        snum += __shfl_xor(snum, m, 64);
        sxx  += __shfl_xor(sxx,  m, 64);
        spp  += __shfl_xor(spp,  m, 64);
    }
    const float corr = snum / (sqrtf(spp) * sqrtf(sxx));

    // ---- soft-DTW, w-domain, 2-group packed, exact per-substep scales ----
    float2v x2[4];
    #pragma unroll
    for (int i = 0; i < 4; ++i) { x2[i].x = x[i]; x2[i].y = x[i + 4]; }

    float2v P[4];
    #pragma unroll
    for (int k = 0; k < 4; ++k) P[k] = (float2v){0.0f, 0.0f};
    int   E = 0;
    float c7w = 0.0f; int c7E = 0;    // published boundary (B-tail, row 8l+7)
    float aT = 0.0f, aT2 = 0.0f;      // A-tail (row 8l+3) delay line -> B-chain
    float pW = 0.0f;  int pE = 0;     // lane l-1 B-tail, two substeps back
    int   vj0 = -2 * lane;            // A-group col for upcoming substep
    const float adoptW = lane0 ? 1.0f : 0.0f;  // diag at adopt: origin / BIG

    // y pipeline: before substep s, zA(l) = y[s-2l], zB(l) = y[s-1-2l]
    // (2-substep-per-lane delay: zA' = dpp(zB_old), zB' = zA_old)
    float zA = lane0 ? y8[0] : 0.0f;
    float zB = 0.0f;

    #pragma unroll 1
    for (int blk = 0; blk < 80; ++blk) {
        // lane-0 feed values y[8*blk+1 .. 8*blk+8] (uniform source lanes;
        // beyond-range garbage is consumed only by dead cells)
        const int us  = blk < 63 ? blk : 63;
        const int us1 = blk < 62 ? blk + 1 : 63;
        float f[8];
        f[0] = rdlane_f(y8[1], us);
        f[1] = rdlane_f(y8[2], us);
        f[2] = rdlane_f(y8[3], us);
        f[3] = rdlane_f(y8[4], us);
        f[4] = rdlane_f(y8[5], us);
        f[5] = rdlane_f(y8[6], us);
        f[6] = rdlane_f(y8[7], us);
        f[7] = rdlane_f(y8[0], us1);

        #pragma unroll
        for (int q = 0; q < 8; ++q) {
            float nW  = dpp_up1_f(c7w);   // lane l-1 B-tail at col j0 (scale nEc)
            int   nEc = dpp_up1_i(c7E);

            // D-factors (Schraudolph), packed {row k @ zA, row k+4 @ zB};
            // off the critical chain
            float2v z2; z2.x = zA; z2.y = zB;
            float2v fsv[4];
            #pragma unroll
            for (int i = 0; i < 4; ++i) {
                float2v t = x2[i] - z2;
                float2v h = (t * t) * (float2v){SCHR_SCALE, SCHR_SCALE}
                          + (float2v){SCHR_OFF, SCHR_OFF};
                fsv[i].x = __int_as_float((int)h.x);
                fsv[i].y = __int_as_float((int)h.y);
            }

            const bool adopt = (vj0 == 0);
            E = adopt ? nEc : E;          // adopt neighbor scale exactly
            float wuA = ldexpf(nW, E - nEc);   // up for A-head, our scale
            float wdA = ldexpf(pW, E - pE);    // diag for A-head
            wdA = adopt ? adoptW : wdA;        // col -1 = BIG; lane0 origin = 1

            float2v uc, dgn;
            uc.x  = wuA; uc.y  = aT;      // B-head up = own A-tail (s-1)
            dgn.x = wdA; dgn.y = aT2;     // B-head diag = own A-tail (s-2)
            #pragma unroll
            for (int k = 0; k < 4; ++k) {
                float2v wl = P[k];
                float2v a  = fsv[k] * (wl + dgn);   // left+diag, off the chain
                float2v w  = fsv[k] * uc + a;       // packed fma chain
                dgn = wl; P[k] = w; uc = w;
            }
            aT2 = aT; aT = P[3].x;

            const bool pub = ((unsigned)(vj0 - 1) < 512u);  // B col valid
            c7w = pub ? P[3].y : c7w;
            c7E = pub ? E : c7E;
            pW = nW; pE = nEc;

            float zn = dpp_up1_f(zB);     // 2-substep/lane delay line
            zB = zA;
            zA = lane0 ? f[q] : zn;
            ++vj0;
        }

        // per-blk renorm: B-tail -> ~[1,2); rescale (P,E) and the published
        // (c7w,c7E) together — implied u invariant, so snapshots stay exact.
        int ebits = (int)((__float_as_uint(P[3].y) >> 23) & 255u);
        int dsh = 127 - ebits;
        dsh = dsh > 126 ? 126 : (dsh < -126 ? -126 : dsh);
        float sf = exp2i(dsh);
        E += dsh;
        float2v sf2; sf2.x = sf; sf2.y = sf;
        #pragma unroll
        for (int k = 0; k < 4; ++k) P[k] = P[k] * sf2;
        aT *= sf; aT2 *= sf;
        c7w *= sf; c7E += dsh;
    }

    float dtwv = 0.0f;
    if (lane == 63) {
        float u = (float)c7E - __builtin_amdgcn_logf(c7w);  // v_log = log2
        dtwv = fabsf(u) * (1.0f / KSC);                     // |R(511,511)|
    }

    // ---- cross-block accumulate + last-block finalize ----
    int* cnt = (int*)(ws + 8);
    if (lane == 0) {
        atomicAdd(&ws[0], sab);
        atomicAdd(&ws[1], ssq);
        atomicAdd(&ws[2], corr);
    }
    if (lane == 63) atomicAdd(&ws[3], dtwv);
    __threadfence();
    if (lane == 0) {
        int prev = atomicAdd(cnt, 1);
        if (prev == NB - 1) {
            __threadfence();
            float mae  = atomicAdd(&ws[0], 0.0f);
            float sq   = atomicAdd(&ws[1], 0.0f);
            float pccs = atomicAdd(&ws[2], 0.0f);
            float dtws = atomicAdd(&ws[3], 0.0f);
            out[NB * TT + 0] = mae;                          // mae_loss
            out[NB * TT + 1] = 1.0f - pccs * (1.0f / 32.0f); // pcc_loss
            out[NB * TT + 2] = dtws * (1.0f / 32.0f);        // dtw_loss
            out[NB * TT + 3] = sqrtf(sq);                    // rmse_loss
        }
    }
}

extern "C" void kernel_launch(void* const* d_in, const int* in_sizes, int n_in,
                              void* d_out, int out_size, void* d_ws, size_t ws_size,
                              hipStream_t stream) {
    const float* pred_map = (const float*)d_in[0];
    const int*   lat_idx  = (const int*)d_in[1];
    const float* omega    = (const float*)d_in[2];
    const float* omni     = (const float*)d_in[3];
    float* out = (float*)d_out;
    float* ws  = (float*)d_ws;

    hipMemsetAsync(ws, 0, 64, stream);
    fused_kernel<<<NB, 64, 0, stream>>>(pred_map, lat_idx, omega, omni, out, ws);
}